// Round 4
// baseline (394.927 us; speedup 1.0000x reference)
//
#include <hip/hip_runtime.h>
#include <math.h>

#define HW_   40000      // H*W = 200*200
#define NQ_   40000
#define IMGW  200
#define IMGH  200

typedef __bf16 bf16;
typedef __attribute__((ext_vector_type(4))) __bf16 bf16x4;
typedef __attribute__((ext_vector_type(8))) __bf16 bf16x8;
typedef __attribute__((ext_vector_type(4))) float f32x4;

// ---------------------------------------------------------------------------
// Prep: weight cast+transpose only. 896 blocks x 256 = 229376 elements.
// ---------------------------------------------------------------------------
__global__ __launch_bounds__(256) void prep_kernel(
    const float* __restrict__ Wv, const float* __restrict__ Wso,
    const float* __restrict__ Waw, const float* __restrict__ Wo,
    bf16* __restrict__ BtV, bf16* __restrict__ BtOA, bf16* __restrict__ BtO)
{
  int idx = blockIdx.x * 256 + threadIdx.x;
  if (idx < 65536) {
    int k = idx >> 8, n = idx & 255;
    BtV[(size_t)n * 256 + k] = (bf16)Wv[idx];
  } else if (idx < 131072) {
    int j = idx - 65536;
    int k = j >> 7, n = j & 127;
    BtOA[(size_t)n * 512 + k] = (bf16)Wso[j];
  } else if (idx < 163840) {
    int j = idx - 131072;
    int k = j >> 6, n = j & 63;
    BtOA[(size_t)(128 + n) * 512 + k] = (bf16)Waw[j];
  } else if (idx < 229376) {
    int j = idx - 163840;
    int k = j >> 8, n = j & 255;
    BtO[(size_t)n * 256 + k] = (bf16)Wo[j];
  }
}

// ---------------------------------------------------------------------------
// Barrier-free register-streaming MFMA GEMM.
// Skinny-K shapes: B (<=192 KB) is L2-resident; A is the only real traffic.
// NO LDS, NO __syncthreads: A and B fragments load directly global->VGPR
// (fragment layout is lane-row-aligned: lane(quad,l16) holds
//  A[row=..+l16][k=quad*8..+7]; a wave's frag-load = 16 rows x 64 B
//  contiguous segments, fully coalesced). fp32 A converts to bf16 in regs
// (same RNE casts as the old prep -> bit-identical staged values).
// Single-buffered named staging regs => compiler emits counted vmcnt,
// loads stay in flight across iterations (no barrier ever drains them).
// Block: 128 rows x BN, 4 waves (2M x 2N), wave 64 x BN/2,
// 4 x NT16 x 16x16x32 MFMAs per K-step. Epilogue unchanged (verified).
// MODE 0: vproj -> bf16 (nbq,h,pix,hd), +bias0
// MODE 1: offaw -> off_bf (n<128,+bias0) / aw_bf (n>=128,+bias1), bf16
// MODE 2: out   -> fp32 +bias0 +resid
// AF32 1: A rows are 256 fp32 (A0 / A1 halves when KT=512); 0: bf16 rows.
// ---------------------------------------------------------------------------
template<int KT, int MODE, int BN, int AF32>
__global__ __launch_bounds__(256) void mfma_gemm_kernel(
    const void* __restrict__ A0, const void* __restrict__ A1,
    const bf16* __restrict__ Bt,
    const float* __restrict__ bias0, const float* __restrict__ bias1,
    const float* __restrict__ resid,
    void* __restrict__ outp, void* __restrict__ outp2, int M)
{
  constexpr int NT16 = BN / 32;        // n-tiles per wave (8 or 6)
  constexpr int NIT  = KT / 32;        // K-steps (8 or 16)
  const int t    = threadIdx.x;
  const int m0   = blockIdx.x * 128;
  const int w    = t >> 6;
  const int lane = t & 63;
  const int quad = lane >> 4;
  const int l16  = lane & 15;
  const int wm   = (w & 1) * 64;
  const int wn   = (w >> 1) * (BN / 2);

  f32x4 acc[4][NT16] = {};

  // Per-lane element offsets (int32; max ~20.5M elements, fits).
  // A row length is 256 elements in every mode (KT=512 splits into A0/A1).
  int aoff[4];
#pragma unroll
  for (int x = 0; x < 4; ++x) {
    int r = m0 + wm + x * 16 + l16;
    if (r >= M) r = M - 1;             // clamp loads; stores guarded below
    aoff[x] = r * 256 + quad * 8;
  }
  int boff[NT16];
#pragma unroll
  for (int x = 0; x < NT16; ++x)
    boff[x] = (wn + x * 16 + l16) * KT + quad * 8;

  float4 a_f[4][2];   // AF32 staging (raw fp32, 32 VGPR)
  bf16x8 a_h[4];      // !AF32 fragments
  bf16x8 b_r[NT16];   // B fragments

  auto loadA = [&](int it) {
    const int kt = it * 32;
    if (AF32) {
      const float* Ap; int col;
      if (KT == 512) { Ap = (kt < 256) ? (const float*)A0 : (const float*)A1; col = kt & 255; }
      else           { Ap = (const float*)A0; col = kt; }
#pragma unroll
      for (int x = 0; x < 4; ++x) {
        const float4* s = (const float4*)&Ap[(size_t)(aoff[x] + col)];
        a_f[x][0] = s[0];
        a_f[x][1] = s[1];
      }
    } else {
      const bf16* Ap = (const bf16*)A0;
#pragma unroll
      for (int x = 0; x < 4; ++x)
        a_h[x] = *(const bf16x8*)&Ap[(size_t)aoff[x] + kt];
    }
  };
  auto loadB = [&](int it) {
    const int kt = it * 32;
#pragma unroll
    for (int x = 0; x < NT16; ++x)
      b_r[x] = *(const bf16x8*)&Bt[(size_t)boff[x] + kt];
  };

  loadA(0);
  loadB(0);

#pragma unroll
  for (int it = 0; it < NIT; ++it) {
    bf16x8 af[4];
    if (AF32) {
      // convert current A (s_waitcnt lands here), then immediately
      // reissue next A into the freed staging regs -> ~1 iter of HBM cover
#pragma unroll
      for (int x = 0; x < 4; ++x) {
        float4 lo = a_f[x][0], hi = a_f[x][1];
        af[x] = bf16x8{(bf16)lo.x, (bf16)lo.y, (bf16)lo.z, (bf16)lo.w,
                       (bf16)hi.x, (bf16)hi.y, (bf16)hi.z, (bf16)hi.w};
      }
      if (it + 1 < NIT) loadA(it + 1);
    } else {
#pragma unroll
      for (int x = 0; x < 4; ++x) af[x] = a_h[x];
    }
#pragma unroll
    for (int mt = 0; mt < 4; ++mt)
#pragma unroll
      for (int nt = 0; nt < NT16; ++nt)
        acc[mt][nt] = __builtin_amdgcn_mfma_f32_16x16x32_bf16(
            af[mt], b_r[nt], acc[mt][nt], 0, 0, 0);
    // reissue B (and bf16-A) after the MFMAs that read them (WAR-safe;
    // L2-hit latency hidden under next iter's MFMA block)
    if (it + 1 < NIT) {
      if (!AF32) loadA(it + 1);
      loadB(it + 1);
    }
  }

  // ---- epilogue (D: col = lane&15, row = quad*4 + reg) ----
#pragma unroll
  for (int mt = 0; mt < 4; ++mt) {
#pragma unroll
    for (int r = 0; r < 4; ++r) {
      const int gm = m0 + wm + mt * 16 + quad * 4 + r;
      if (gm >= M) continue;
#pragma unroll
      for (int nt = 0; nt < NT16; ++nt) {
        const int gn = wn + nt * 16 + l16;
        float v = acc[mt][nt][r];
        if (MODE == 0) {
          int nbq = (gm >= HW_) ? 1 : 0;
          int pix = gm - nbq * HW_;
          int h = gn >> 5, hd = gn & 31;
          ((bf16*)outp)[(((size_t)(nbq * 8 + h) * HW_ + pix) << 5) + hd] =
              (bf16)(v + bias0[gn]);
        } else if (MODE == 1) {
          if (gn < 128)
            ((bf16*)outp)[(size_t)gm * 128 + gn] = (bf16)(v + bias0[gn]);
          else
            ((bf16*)outp2)[(size_t)gm * 64 + (gn - 128)] =
                (bf16)(v + bias1[gn - 128]);
        } else {
          ((float*)outp)[(size_t)gm * 256 + gn] =
              v + bias0[gn] + resid[(size_t)gm * 256 + gn];
        }
      }
    }
  }
}

// ---------------------------------------------------------------------------
// Deform sampling, XCD-partitioned by head (verified +28% in R2):
//   h = blockIdx.x & 7 pins each head's 5.1 MB vws slice to one XCD's L2.
//   Lane map: lane = qi*8 + nbq*4 + sub; __shfl_xor(...,4) pairs nbq0/nbq1.
// ---------------------------------------------------------------------------
__global__ __launch_bounds__(256) void deform_attn_kernel(
    const bf16* __restrict__ vws,     // (2,8,40000,32) bf16
    const bf16* __restrict__ off_bf,  // (40000,128) bf16
    const bf16* __restrict__ aw_bf,   // (40000,64) bf16
    const float* __restrict__ ref,    // (40000,2)
    bf16* __restrict__ ms)            // (40000,256) bf16
{
  const int t    = threadIdx.x;
  const int w    = t >> 6;
  const int lane = t & 63;
  const int h    = blockIdx.x & 7;        // head pinned to XCD
  const int qb   = blockIdx.x >> 3;       // 0..1249
  const int qi   = lane >> 3;             // 0..7
  const int q    = qb * 32 + w * 8 + qi;
  const int nbq  = (lane >> 2) & 1;
  const int sub  = lane & 3;
  const int g    = h * 2 + nbq;

  const float rx = ref[2 * q + 0] * (float)IMGW - 0.5f;
  const float ry = ref[2 * q + 1] * (float)IMGH - 0.5f;

  bf16x4 a4 = *(const bf16x4*)&aw_bf[(size_t)q * 64 + g * 4];
  float aa0 = (float)a4[0], aa1 = (float)a4[1], aa2 = (float)a4[2], aa3 = (float)a4[3];
  float mx = fmaxf(fmaxf(aa0, aa1), fmaxf(aa2, aa3));
  float e0 = __expf(aa0 - mx), e1 = __expf(aa1 - mx);
  float e2 = __expf(aa2 - mx), e3 = __expf(aa3 - mx);
  float inv = 1.0f / (e0 + e1 + e2 + e3);
  float w4[4] = {e0 * inv, e1 * inv, e2 * inv, e3 * inv};

  bf16x8 o8 = *(const bf16x8*)&off_bf[(size_t)q * 128 + g * 8];
  float ox[4] = {(float)o8[0], (float)o8[2], (float)o8[4], (float)o8[6]};
  float oy[4] = {(float)o8[1], (float)o8[3], (float)o8[5], (float)o8[7]};

  const bf16* vbase = vws + (((size_t)(nbq * 8 + h) * HW_) << 5) + sub * 8;

  float acc[8] = {};
#pragma unroll
  for (int p = 0; p < 4; ++p) {
    float x = rx + ox[p];
    float y = ry + oy[p];
    float xf = floorf(x), yf = floorf(y);
    int   x0 = (int)xf,   y0 = (int)yf;
    float lx = x - xf,    ly = y - yf;
    int   x1 = x0 + 1,    y1 = y0 + 1;
    float w00 = (1.0f - lx) * (1.0f - ly);
    float w01 = lx * (1.0f - ly);
    float w10 = (1.0f - lx) * ly;
    float w11 = lx * ly;
    if (x0 < 0 || x0 >= IMGW) { w00 = 0.0f; w10 = 0.0f; }
    if (x1 < 0 || x1 >= IMGW) { w01 = 0.0f; w11 = 0.0f; }
    if (y0 < 0 || y0 >= IMGH) { w00 = 0.0f; w01 = 0.0f; }
    if (y1 < 0 || y1 >= IMGH) { w10 = 0.0f; w11 = 0.0f; }
    int xc0 = min(max(x0, 0), IMGW - 1), xc1 = min(max(x1, 0), IMGW - 1);
    int yc0 = min(max(y0, 0), IMGH - 1), yc1 = min(max(y1, 0), IMGH - 1);
    bf16x8 v00 = *(const bf16x8*)&vbase[(size_t)(yc0 * IMGW + xc0) << 5];
    bf16x8 v01 = *(const bf16x8*)&vbase[(size_t)(yc0 * IMGW + xc1) << 5];
    bf16x8 v10 = *(const bf16x8*)&vbase[(size_t)(yc1 * IMGW + xc0) << 5];
    bf16x8 v11 = *(const bf16x8*)&vbase[(size_t)(yc1 * IMGW + xc1) << 5];
    float wp = w4[p];
#pragma unroll
    for (int j = 0; j < 8; ++j) {
      float s = w00 * (float)v00[j] + w01 * (float)v01[j] +
                w10 * (float)v10[j] + w11 * (float)v11[j];
      acc[j] = fmaf(wp, s, acc[j]);
    }
  }

#pragma unroll
  for (int j = 0; j < 8; ++j) acc[j] += __shfl_xor(acc[j], 4);

  if (nbq == 0) {
    bf16x8 o;
#pragma unroll
    for (int j = 0; j < 8; ++j) o[j] = (bf16)(0.5f * acc[j]);
    *(bf16x8*)&ms[(size_t)q * 256 + h * 32 + sub * 8] = o;
  }
}

extern "C" void kernel_launch(void* const* d_in, const int* in_sizes, int n_in,
                              void* d_out, int out_size, void* d_ws, size_t ws_size,
                              hipStream_t stream) {
  const float* query = (const float*)d_in[0];   // (1, 40000, 256)
  const float* value = (const float*)d_in[1];   // (1, 80000, 256)
  const float* ref   = (const float*)d_in[2];   // (1, 40000, 1, 2)
  const float* Wv  = (const float*)d_in[4];
  const float* bv  = (const float*)d_in[5];
  const float* Wso = (const float*)d_in[6];
  const float* bso = (const float*)d_in[7];
  const float* Waw = (const float*)d_in[8];
  const float* baw = (const float*)d_in[9];
  const float* Wo  = (const float*)d_in[10];
  const float* bo  = (const float*)d_in[11];
  float* out = (float*)d_out;

  char* p = (char*)d_ws;
  bf16* vws    = (bf16*)p; p += (size_t)2 * 8 * HW_ * 32 * 2;   // 40.96 MB
  bf16* off_bf = (bf16*)p; p += (size_t)NQ_ * 128 * 2;          // 10.24 MB
  bf16* aw_bf  = (bf16*)p; p += (size_t)NQ_ * 64 * 2;           //  5.12 MB
  bf16* ms     = (bf16*)p; p += (size_t)NQ_ * 256 * 2;          // 20.48 MB
  bf16* BtV    = (bf16*)p; p += (size_t)256 * 256 * 2;
  bf16* BtOA   = (bf16*)p; p += (size_t)192 * 512 * 2;
  bf16* BtO    = (bf16*)p; p += (size_t)256 * 256 * 2;

  // weights only (value/query conversion fused into GEMM A-loads)
  prep_kernel<<<896, 256, 0, stream>>>(Wv, Wso, Waw, Wo, BtV, BtOA, BtO);

  // vproj: value fp32 (80000x256) @ (256x256) -> bf16 (2,8,40000,32)
  mfma_gemm_kernel<256, 0, 256, 1><<<625, 256, 0, stream>>>(
      value, nullptr, BtV, bv, nullptr, nullptr, vws, nullptr, 2 * HW_);
  // offaw: qe = [value[:40000] | query] fp32 (40000x512) @ (512x192)
  mfma_gemm_kernel<512, 1, 192, 1><<<313, 256, 0, stream>>>(
      value, query, BtOA, bso, baw, nullptr, off_bf, aw_bf, NQ_);
  // sampling (XCD-partitioned by head)
  deform_attn_kernel<<<10000, 256, 0, stream>>>(vws, off_bf, aw_bf, ref, ms);
  // out: ms bf16 (40000x256) @ (256x256) + b + residual
  mfma_gemm_kernel<256, 2, 256, 0><<<313, 256, 0, stream>>>(
      ms, nullptr, BtO, bo, nullptr, query, out, nullptr, NQ_);
}

// Round 5
// 293.479 us; speedup vs baseline: 1.3457x; 1.3457x over previous
//
#include <hip/hip_runtime.h>
#include <math.h>

#define HW_   40000      // H*W = 200*200
#define NQ_   40000
#define IMGW  200
#define IMGH  200

typedef __bf16 bf16;
typedef __attribute__((ext_vector_type(4))) __bf16 bf16x4;
typedef __attribute__((ext_vector_type(8))) __bf16 bf16x8;
typedef __attribute__((ext_vector_type(4))) float f32x4;

__device__ __forceinline__ void gload_lds16(const void* g, void* l) {
  __builtin_amdgcn_global_load_lds(
      (const __attribute__((address_space(1))) void*)g,
      (__attribute__((address_space(3))) void*)l, 16, 0, 0);
}

// ---------------------------------------------------------------------------
// Prep: weight cast+transpose only. 896 blocks x 256 = 229376 elements.
// ---------------------------------------------------------------------------
__global__ __launch_bounds__(256) void prep_kernel(
    const float* __restrict__ Wv, const float* __restrict__ Wso,
    const float* __restrict__ Waw, const float* __restrict__ Wo,
    bf16* __restrict__ BtV, bf16* __restrict__ BtOA, bf16* __restrict__ BtO)
{
  int idx = blockIdx.x * 256 + threadIdx.x;
  if (idx < 65536) {
    int k = idx >> 8, n = idx & 255;
    BtV[(size_t)n * 256 + k] = (bf16)Wv[idx];
  } else if (idx < 131072) {
    int j = idx - 65536;
    int k = j >> 7, n = j & 127;
    BtOA[(size_t)n * 512 + k] = (bf16)Wso[j];
  } else if (idx < 163840) {
    int j = idx - 131072;
    int k = j >> 6, n = j & 63;
    BtOA[(size_t)(128 + n) * 512 + k] = (bf16)Waw[j];
  } else if (idx < 229376) {
    int j = idx - 163840;
    int k = j >> 8, n = j & 255;
    BtO[(size_t)n * 256 + k] = (bf16)Wo[j];
  }
}

// ---------------------------------------------------------------------------
// MFMA bf16 GEMM, 64 x BN block (R3 LDS structure + 2 fixes):
//  * 64-row tiles (was 128): 2x grid -> ~4-5 blocks/CU (LDS 40KB, VGPR ~100),
//    so the per-iteration barrier drain overlaps across more resident waves.
//  * LDS slot-swizzle (slot ^= (row>>1)&3 on 16B chunks): fragment reads
//    were 8-way bank conflicts (960K measured in R3), now 2-way (b128 floor).
//    Reg-staged A swizzles the ds_write; global_load_lds paths keep a linear
//    LDS dest and permute the GLOBAL source chunk (rule: both-sides-or-
//    neither; source perm stays within one 64B segment -> still coalesced).
// BK=32, double-buffered, one barrier/iter, next tile issued post-barrier.
// 4 waves, 2M x 2N: wave = 32 rows x BN/2, 2 x NT16 MFMAs per K-step.
// MODE 0: vproj -> bf16 (nbq,h,pix,hd), +bias0
// MODE 1: offaw -> off_bf (n<128,+bias0) / aw_bf (n>=128,+bias1), bf16
// MODE 2: out   -> fp32 +bias0 +resid
// AF32 1: A rows are 256 fp32 (A0/A1 halves when KT=512), reg-convert;
//      0: A rows are 256 bf16 via global_load_lds.
// ---------------------------------------------------------------------------
template<int KT, int MODE, int BN, int AF32>
__global__ __launch_bounds__(256) void mfma_gemm_kernel(
    const void* __restrict__ A0, const void* __restrict__ A1,
    const bf16* __restrict__ Bt,
    const float* __restrict__ bias0, const float* __restrict__ bias1,
    const float* __restrict__ resid,
    void* __restrict__ outp, void* __restrict__ outp2, int M)
{
  constexpr int NT16 = BN / 32;        // n-tiles per wave (8 or 6)
  constexpr int BCH  = BN / 64;        // B 16-B chunks per thread (4 or 3)
  constexpr int NIT  = KT / 32;        // K-steps (8 or 16)
  __shared__ bf16 As[2][64 * 32];      // 2 x 4 KB
  __shared__ bf16 Bs[2][BN * 32];      // 2 x 16/12 KB
  const int t    = threadIdx.x;
  const int m0   = blockIdx.x * 64;
  const int w    = t >> 6;
  const int lane = t & 63;
  const int quad = lane >> 4;
  const int l16  = lane & 15;
  const int wm   = (w & 1) * 32;
  const int wn   = (w >> 1) * (BN / 2);

  f32x4 acc[2][NT16] = {};

  // A staging: 1 chunk/thread; local row = t>>2, source kchunk = t&3
  int gmA;
  {
    int gm = m0 + (t >> 2);
    gmA = (gm >= M) ? (M - 1) : gm;
  }
  const int arow = t >> 2;
  const int akey = (arow >> 1) & 3;

  float4 apf[2];      // AF32 staging regs (8 fp32)

  auto issueB = [&](int it) {
    const int kt  = it * 32;
    const int buf = it & 1;
#pragma unroll
    for (int i = 0; i < BCH; ++i) {
      int c   = i * 256 + t;
      int row = c >> 2;
      int j   = (c & 3) ^ ((row >> 1) & 3);     // source-chunk permutation
      gload_lds16(&Bt[(size_t)row * KT + kt + j * 8], &Bs[buf][c * 8]);
    }
  };

  auto issueA_lds = [&](int it) {               // bf16 A (MODE 2)
    const int kt  = it * 32;
    const int buf = it & 1;
    const bf16* Ap = (const bf16*)A0;
    int j = (t & 3) ^ akey;                     // source-chunk permutation
    gload_lds16(&Ap[(size_t)gmA * 256 + kt + j * 8], &As[buf][t * 8]);
  };

  auto loadA_f32 = [&](int it) {                // fp32 A -> regs (linear src)
    const int kt = it * 32;
    const float* Ap; int col;
    if (KT == 512) { Ap = (kt < 256) ? (const float*)A0 : (const float*)A1; col = kt & 255; }
    else           { Ap = (const float*)A0; col = kt; }
    const float4* s4 = (const float4*)&Ap[(size_t)gmA * 256 + col + (t & 3) * 8];
    apf[0] = s4[0];
    apf[1] = s4[1];
  };

  auto writeA = [&](int it) {                   // convert + swizzled ds_write
    const int buf = it & 1;
    int j = (t & 3) ^ akey;
    bf16x8 o = {(bf16)apf[0].x, (bf16)apf[0].y, (bf16)apf[0].z, (bf16)apf[0].w,
                (bf16)apf[1].x, (bf16)apf[1].y, (bf16)apf[1].z, (bf16)apf[1].w};
    *(bf16x8*)&As[buf][arow * 32 + j * 8] = o;
  };

  if (AF32) { loadA_f32(0); issueB(0); writeA(0); }
  else      { issueA_lds(0); issueB(0); }

#pragma unroll
  for (int it = 0; it < NIT; ++it) {
    __syncthreads();                       // drains tile-it loads/writes
    if (it + 1 < NIT) {                    // overlaps the MFMA block below
      issueB(it + 1);
      if (AF32) loadA_f32(it + 1); else issueA_lds(it + 1);
    }
    const bf16* as = As[it & 1];
    const bf16* bs = Bs[it & 1];
    bf16x8 af[2], bfr[NT16];
#pragma unroll
    for (int x = 0; x < 2; ++x) {
      int row = wm + x * 16 + l16;
      af[x] = *(const bf16x8*)&as[row * 32 + (quad ^ ((row >> 1) & 3)) * 8];
    }
#pragma unroll
    for (int x = 0; x < NT16; ++x) {
      int row = wn + x * 16 + l16;
      bfr[x] = *(const bf16x8*)&bs[row * 32 + (quad ^ ((row >> 1) & 3)) * 8];
    }
#pragma unroll
    for (int mt = 0; mt < 2; ++mt)
#pragma unroll
      for (int nt = 0; nt < NT16; ++nt)
        acc[mt][nt] = __builtin_amdgcn_mfma_f32_16x16x32_bf16(
            af[mt], bfr[nt], acc[mt][nt], 0, 0, 0);
    if (AF32 && it + 1 < NIT) writeA(it + 1);   // to the free buffer
  }

  // ---- epilogue (D: col = lane&15, row = quad*4 + reg) ----
#pragma unroll
  for (int mt = 0; mt < 2; ++mt) {
#pragma unroll
    for (int r = 0; r < 4; ++r) {
      const int gm = m0 + wm + mt * 16 + quad * 4 + r;
      if (gm >= M) continue;
#pragma unroll
      for (int nt = 0; nt < NT16; ++nt) {
        const int gn = wn + nt * 16 + l16;
        float v = acc[mt][nt][r];
        if (MODE == 0) {
          int nbq = (gm >= HW_) ? 1 : 0;
          int pix = gm - nbq * HW_;
          int h = gn >> 5, hd = gn & 31;
          ((bf16*)outp)[(((size_t)(nbq * 8 + h) * HW_ + pix) << 5) + hd] =
              (bf16)(v + bias0[gn]);
        } else if (MODE == 1) {
          if (gn < 128)
            ((bf16*)outp)[(size_t)gm * 128 + gn] = (bf16)(v + bias0[gn]);
          else
            ((bf16*)outp2)[(size_t)gm * 64 + (gn - 128)] =
                (bf16)(v + bias1[gn - 128]);
        } else {
          ((float*)outp)[(size_t)gm * 256 + gn] =
              v + bias0[gn] + resid[(size_t)gm * 256 + gn];
        }
      }
    }
  }
}

// ---------------------------------------------------------------------------
// Deform sampling, XCD-partitioned by head (verified +28% in R2):
//   h = blockIdx.x & 7 pins each head's 5.1 MB vws slice to one XCD's L2.
//   Lane map: lane = qi*8 + nbq*4 + sub; __shfl_xor(...,4) pairs nbq0/nbq1.
// ---------------------------------------------------------------------------
__global__ __launch_bounds__(256) void deform_attn_kernel(
    const bf16* __restrict__ vws,     // (2,8,40000,32) bf16
    const bf16* __restrict__ off_bf,  // (40000,128) bf16
    const bf16* __restrict__ aw_bf,   // (40000,64) bf16
    const float* __restrict__ ref,    // (40000,2)
    bf16* __restrict__ ms)            // (40000,256) bf16
{
  const int t    = threadIdx.x;
  const int w    = t >> 6;
  const int lane = t & 63;
  const int h    = blockIdx.x & 7;        // head pinned to XCD
  const int qb   = blockIdx.x >> 3;       // 0..1249
  const int qi   = lane >> 3;             // 0..7
  const int q    = qb * 32 + w * 8 + qi;
  const int nbq  = (lane >> 2) & 1;
  const int sub  = lane & 3;
  const int g    = h * 2 + nbq;

  const float rx = ref[2 * q + 0] * (float)IMGW - 0.5f;
  const float ry = ref[2 * q + 1] * (float)IMGH - 0.5f;

  bf16x4 a4 = *(const bf16x4*)&aw_bf[(size_t)q * 64 + g * 4];
  float aa0 = (float)a4[0], aa1 = (float)a4[1], aa2 = (float)a4[2], aa3 = (float)a4[3];
  float mx = fmaxf(fmaxf(aa0, aa1), fmaxf(aa2, aa3));
  float e0 = __expf(aa0 - mx), e1 = __expf(aa1 - mx);
  float e2 = __expf(aa2 - mx), e3 = __expf(aa3 - mx);
  float inv = 1.0f / (e0 + e1 + e2 + e3);
  float w4[4] = {e0 * inv, e1 * inv, e2 * inv, e3 * inv};

  bf16x8 o8 = *(const bf16x8*)&off_bf[(size_t)q * 128 + g * 8];
  float ox[4] = {(float)o8[0], (float)o8[2], (float)o8[4], (float)o8[6]};
  float oy[4] = {(float)o8[1], (float)o8[3], (float)o8[5], (float)o8[7]};

  const bf16* vbase = vws + (((size_t)(nbq * 8 + h) * HW_) << 5) + sub * 8;

  float acc[8] = {};
#pragma unroll
  for (int p = 0; p < 4; ++p) {
    float x = rx + ox[p];
    float y = ry + oy[p];
    float xf = floorf(x), yf = floorf(y);
    int   x0 = (int)xf,   y0 = (int)yf;
    float lx = x - xf,    ly = y - yf;
    int   x1 = x0 + 1,    y1 = y0 + 1;
    float w00 = (1.0f - lx) * (1.0f - ly);
    float w01 = lx * (1.0f - ly);
    float w10 = (1.0f - lx) * ly;
    float w11 = lx * ly;
    if (x0 < 0 || x0 >= IMGW) { w00 = 0.0f; w10 = 0.0f; }
    if (x1 < 0 || x1 >= IMGW) { w01 = 0.0f; w11 = 0.0f; }
    if (y0 < 0 || y0 >= IMGH) { w00 = 0.0f; w01 = 0.0f; }
    if (y1 < 0 || y1 >= IMGH) { w10 = 0.0f; w11 = 0.0f; }
    int xc0 = min(max(x0, 0), IMGW - 1), xc1 = min(max(x1, 0), IMGW - 1);
    int yc0 = min(max(y0, 0), IMGH - 1), yc1 = min(max(y1, 0), IMGH - 1);
    bf16x8 v00 = *(const bf16x8*)&vbase[(size_t)(yc0 * IMGW + xc0) << 5];
    bf16x8 v01 = *(const bf16x8*)&vbase[(size_t)(yc0 * IMGW + xc1) << 5];
    bf16x8 v10 = *(const bf16x8*)&vbase[(size_t)(yc1 * IMGW + xc0) << 5];
    bf16x8 v11 = *(const bf16x8*)&vbase[(size_t)(yc1 * IMGW + xc1) << 5];
    float wp = w4[p];
#pragma unroll
    for (int j = 0; j < 8; ++j) {
      float s = w00 * (float)v00[j] + w01 * (float)v01[j] +
                w10 * (float)v10[j] + w11 * (float)v11[j];
      acc[j] = fmaf(wp, s, acc[j]);
    }
  }

#pragma unroll
  for (int j = 0; j < 8; ++j) acc[j] += __shfl_xor(acc[j], 4);

  if (nbq == 0) {
    bf16x8 o;
#pragma unroll
    for (int j = 0; j < 8; ++j) o[j] = (bf16)(0.5f * acc[j]);
    *(bf16x8*)&ms[(size_t)q * 256 + h * 32 + sub * 8] = o;
  }
}

extern "C" void kernel_launch(void* const* d_in, const int* in_sizes, int n_in,
                              void* d_out, int out_size, void* d_ws, size_t ws_size,
                              hipStream_t stream) {
  const float* query = (const float*)d_in[0];   // (1, 40000, 256)
  const float* value = (const float*)d_in[1];   // (1, 80000, 256)
  const float* ref   = (const float*)d_in[2];   // (1, 40000, 1, 2)
  const float* Wv  = (const float*)d_in[4];
  const float* bv  = (const float*)d_in[5];
  const float* Wso = (const float*)d_in[6];
  const float* bso = (const float*)d_in[7];
  const float* Waw = (const float*)d_in[8];
  const float* baw = (const float*)d_in[9];
  const float* Wo  = (const float*)d_in[10];
  const float* bo  = (const float*)d_in[11];
  float* out = (float*)d_out;

  char* p = (char*)d_ws;
  bf16* vws    = (bf16*)p; p += (size_t)2 * 8 * HW_ * 32 * 2;   // 40.96 MB
  bf16* off_bf = (bf16*)p; p += (size_t)NQ_ * 128 * 2;          // 10.24 MB
  bf16* aw_bf  = (bf16*)p; p += (size_t)NQ_ * 64 * 2;           //  5.12 MB
  bf16* ms     = (bf16*)p; p += (size_t)NQ_ * 256 * 2;          // 20.48 MB
  bf16* BtV    = (bf16*)p; p += (size_t)256 * 256 * 2;
  bf16* BtOA   = (bf16*)p; p += (size_t)192 * 512 * 2;
  bf16* BtO    = (bf16*)p; p += (size_t)256 * 256 * 2;

  // weights only (value/query conversion fused into GEMM A-staging)
  prep_kernel<<<896, 256, 0, stream>>>(Wv, Wso, Waw, Wo, BtV, BtOA, BtO);

  // vproj: value fp32 (80000x256) @ (256x256) -> bf16 (2,8,40000,32)
  mfma_gemm_kernel<256, 0, 256, 1><<<1250, 256, 0, stream>>>(
      value, nullptr, BtV, bv, nullptr, nullptr, vws, nullptr, 2 * HW_);
  // offaw: qe = [value[:40000] | query] fp32 (40000x512) @ (512x192)
  mfma_gemm_kernel<512, 1, 192, 1><<<625, 256, 0, stream>>>(
      value, query, BtOA, bso, baw, nullptr, off_bf, aw_bf, NQ_);
  // sampling (XCD-partitioned by head)
  deform_attn_kernel<<<10000, 256, 0, stream>>>(vws, off_bf, aw_bf, ref, ms);
  // out: ms bf16 (40000x256) @ (256x256) + b + residual
  mfma_gemm_kernel<256, 2, 256, 0><<<625, 256, 0, stream>>>(
      ms, nullptr, BtO, bo, nullptr, query, out, nullptr, NQ_);
}